// Round 8
// baseline (90.937 us; speedup 1.0000x reference)
//
#include <hip/hip_runtime.h>

// NIoULoss_pixel: B=8, N=8, H=W=512. One-pass fused reduction.
// R8: structural TLP fix. R2-R7 proved per-thread ILP (24-load batch) is
// unachievable (VGPR stuck 48-100, ~1-2 loads in flight/wave, 44us plateau).
// New shape: block = 256 pixels. Phase 1: thread -> ONE pixel's dn/po/go
// (8 scalar coalesced loads) -> LDS. Phase 2: thread (g,q) -> planes 2g,2g+1
// of quad q: 4 int4 mask loads + LDS reads. Only 12 loads/thread, masks
// consumed after the barrier window -> latency hidden structurally.
// Wave w owns plane-pair w: epilogue = wave-reduce + lane0 atomics only.

constexpr int Bc  = 8;
constexpr int Nc  = 8;
constexpr int HWc = 512 * 512;
constexpr int PAD = 16;               // floats per counter slot (64 B line)
constexpr float EPSc = 1e-6f;

__device__ __forceinline__ float gload_f1(const float* a) {
    float r;
    asm volatile("global_load_dword %0, %1, off" : "=v"(r) : "v"(a) : "memory");
    return r;
}
__device__ __forceinline__ int4 gload_i4(const int* a) {
    int4 r;
    asm volatile("global_load_dwordx4 %0, %1, off" : "=v"(r) : "v"(a) : "memory");
    return r;
}
#define WAITV(n_) do {                                                   \
        asm volatile("s_waitcnt vmcnt(" #n_ ")" ::: "memory");           \
        __builtin_amdgcn_sched_barrier(0);                               \
    } while (0)

__device__ __forceinline__ float wave_reduce(float v) {
#pragma unroll
    for (int off = 32; off; off >>= 1) v += __shfl_xor(v, off, 64);
    return v;
}

// 1024 blocks per image, 256 threads/block, 256 pixels/block.
__global__ __launch_bounds__(256, 6) void niou_partial(
    const float* __restrict__ pd, const float* __restrict__ gt,
    const int* __restrict__ pmask, const int* __restrict__ gmask,
    float* __restrict__ ws /* [B][40][PAD] */)
{
    __shared__ float dnL[264], poL[264], goL[264];   // sidx(p)=p+(p>>5): conflict-free

    const int tid  = threadIdx.x;
    const int b    = blockIdx.x >> 10;
    const int blk  = blockIdx.x & 1023;
    const int base = blk * 256;                 // first pixel of this block
    const int pix  = base + tid;

    // ---- issue rgbo loads (oldest in vmcnt queue): 8 scalar coalesced ----
    const float* pdB = pd + (size_t)b * 4 * HWc + pix;
    const float* gtB = gt + (size_t)b * 4 * HWc + pix;
    float pr[4], gr[4];
#pragma unroll
    for (int c = 0; c < 4; ++c) pr[c] = gload_f1(pdB + (size_t)c * HWc);
#pragma unroll
    for (int c = 0; c < 4; ++c) gr[c] = gload_f1(gtB + (size_t)c * HWc);

    // ---- issue mask loads: thread (g,q) -> planes 2g,2g+1 at quad q ----
    const int g = tid >> 6, q = tid & 63;
    const int qb = base + 4 * q;
    const int* pm0 = pmask + ((size_t)(b * Nc + 2 * g    )) * HWc + qb;
    const int* gm0 = gmask + ((size_t)(b * Nc + 2 * g    )) * HWc + qb;
    const int* pm1 = pmask + ((size_t)(b * Nc + 2 * g + 1)) * HWc + qb;
    const int* gm1 = gmask + ((size_t)(b * Nc + 2 * g + 1)) * HWc + qb;
    int4 pmv[2], gmv[2];
    pmv[0] = gload_i4(pm0); gmv[0] = gload_i4(gm0);
    pmv[1] = gload_i4(pm1); gmv[1] = gload_i4(gm1);

    // ---- rgbo ready (8 oldest done); 4 mask loads still in flight ----
    WAITV(4);
    {
        const float dx = pr[0] - gr[0], dy = pr[1] - gr[1], dz = pr[2] - gr[2];
        const int si = tid + (tid >> 5);
        dnL[si] = sqrtf(dx * dx + dy * dy + dz * dz);
        poL[si] = rintf(pr[3]);
        goL[si] = rintf(gr[3]);
    }
    __syncthreads();

    // ---- masks guaranteed complete; consume from regs + LDS ----
    WAITV(0);
    float dn[4], po[4], go[4];
#pragma unroll
    for (int j = 0; j < 4; ++j) {
        const int p4 = 4 * q + j, s4 = p4 + (p4 >> 5);
        dn[j] = dnL[s4]; po[j] = poL[s4]; go[j] = goL[s4];
    }

    // acc[pp]: {sim_sum, inter, gt_sum, s_sum}; count via ballot
    float acc[2][4];
    int   wcnt[2];
#pragma unroll
    for (int pp = 0; pp < 2; ++pp) {
        wcnt[pp] = 0;
#pragma unroll
        for (int k = 0; k < 4; ++k) acc[pp][k] = 0.f;
    }

#pragma unroll
    for (int pp = 0; pp < 2; ++pp) {
        const int pmx[4] = {pmv[pp].x, pmv[pp].y, pmv[pp].z, pmv[pp].w};
        const int gmx[4] = {gmv[pp].x, gmv[pp].y, gmv[pp].z, gmv[pp].w};
#pragma unroll
        for (int j = 0; j < 4; ++j) {
            const bool P = pmx[j] != 0;
            const bool G = gmx[j] != 0;
            wcnt[pp] += __popcll(__ballot(P));
            const float s = P ? po[j] : 0.f;
            acc[pp][0] += P ? dn[j] : 0.f;
            acc[pp][1] += G ? s     : 0.f;   // inter = (P&&G)?po:0
            acc[pp][2] += G ? go[j] : 0.f;
            acc[pp][3] += s;                 // xor = s_sum - inter (in final)
        }
    }

    // ---- wave-level reduction: wave g owns planes 2g,2g+1 exclusively ----
    const int lane = tid & 63;
#pragma unroll
    for (int pp = 0; pp < 2; ++pp) {
        const float s0 = wave_reduce(acc[pp][0]);
        const float s1 = wave_reduce(acc[pp][1]);
        const float s2 = wave_reduce(acc[pp][2]);
        const float s3 = wave_reduce(acc[pp][3]);
        if (lane == 0) {
            const int n = 2 * g + pp;
            float* wsn = &ws[(b * 40 + n * 5) * PAD];
            atomicAdd(&wsn[0 * PAD], s0);               // sim
            atomicAdd(&wsn[1 * PAD], (float)wcnt[pp]);  // count
            atomicAdd(&wsn[2 * PAD], s1);               // inter
            atomicAdd(&wsn[3 * PAD], s2);               // gt_sum
            atomicAdd(&wsn[4 * PAD], s3);               // s_sum
        }
    }
}

__global__ __launch_bounds__(64) void niou_final(
    const float* __restrict__ ws, float* __restrict__ out)
{
    const int t = threadIdx.x;   // 0..63 == b*8+n
    const float* w = ws + (size_t)t * 5 * PAD;
    const float sim   = w[0 * PAD];
    const float cnt   = w[1 * PAD];
    const float inter = w[2 * PAD];
    const float gts   = w[3 * PAD];
    const float ssum  = w[4 * PAD];
    const float xo    = ssum - inter;            // pd_xor_sum
    const float punish = sim / (cnt + EPSc);
    const float iou    = inter / (gts + xo + EPSc);
    float term = 1.0f - iou + punish;
#pragma unroll
    for (int off = 32; off; off >>= 1) term += __shfl_xor(term, off, 64);
    if (t == 0) out[0] = term * (1.0f / 64.0f);
}

extern "C" void kernel_launch(void* const* d_in, const int* in_sizes, int n_in,
                              void* d_out, int out_size, void* d_ws, size_t ws_size,
                              hipStream_t stream) {
    const float* pd_rgbo = (const float*)d_in[0];
    const float* gt_rgbo = (const float*)d_in[1];
    const int*   pd_mask = (const int*)d_in[2];
    const int*   gt_mask = (const int*)d_in[3];
    float* out = (float*)d_out;
    float* ws  = (float*)d_ws;

    hipMemsetAsync(ws, 0, Bc * 40 * PAD * sizeof(float), stream);
    niou_partial<<<Bc * 1024, 256, 0, stream>>>(pd_rgbo, gt_rgbo, pd_mask, gt_mask, ws);
    niou_final<<<1, 64, 0, stream>>>(ws, out);
}

// Round 9
// 55.071 us; speedup vs baseline: 1.6513x; 1.6513x over previous
//
#include <hip/hip_runtime.h>

// NIoULoss_pixel: B=8, N=8, H=W=512. One-pass fused reduction.
// R9: R4's proven fat-batch structure (best per-wave MLP measured: 24 plain
// HIP loads/iter + sched_barrier, VGPR 84) x 2 the resident waves:
// 128-thread blocks, R=2 quads/thread, 2048 blocks (8/CU, 16 waves/CU via
// __launch_bounds__(128,4)). R8's lesson applied: atomics stay at 40/block
// (82K total, ~256 per address) and all loads stay 16B vector.

constexpr int Bc  = 8;
constexpr int Nc  = 8;
constexpr int HWc = 512 * 512;
constexpr int PAD = 16;               // floats per counter slot (64 B line)
constexpr int R   = 2;                // quads per thread
constexpr int TPB = 128;              // threads per block (2 waves)
constexpr int QPB = TPB * R;          // quads per block = 256
constexpr float EPSc = 1e-6f;

__device__ __forceinline__ float wave_reduce(float v) {
#pragma unroll
    for (int off = 32; off; off >>= 1) v += __shfl_xor(v, off, 64);
    return v;
}

// 256 blocks per image, 128 threads/block, R=2 quads per thread.
__global__ __launch_bounds__(TPB, 4) void niou_partial(
    const float* __restrict__ pd, const float* __restrict__ gt,
    const int* __restrict__ pmask, const int* __restrict__ gmask,
    float* __restrict__ ws /* [B][40][PAD] */)
{
    const int b   = blockIdx.x >> 8;
    const int blk = blockIdx.x & 255;
    const int tid = threadIdx.x;
    constexpr int HW4 = HWc / 4;

    // acc[n]: {sim_sum, inter, gt_sum, s_sum}; count via ballot (wave-uniform)
    float acc[Nc][4];
    int   wcnt[Nc];
#pragma unroll
    for (int n = 0; n < Nc; ++n) {
        wcnt[n] = 0;
#pragma unroll
        for (int q = 0; q < 4; ++q) acc[n][q] = 0.f;
    }

#pragma unroll
    for (int r = 0; r < R; ++r) {
        const int quad = blk * QPB + r * TPB + tid;
        const size_t p = (size_t)quad * 4;

        const float4* pd4 = reinterpret_cast<const float4*>(pd + (size_t)b * 4 * HWc + p);
        const float4* gt4 = reinterpret_cast<const float4*>(gt + (size_t)b * 4 * HWc + p);
        const int4*   pm4 = reinterpret_cast<const int4*>(pmask + (size_t)b * Nc * HWc + p);
        const int4*   gm4 = reinterpret_cast<const int4*>(gmask + (size_t)b * Nc * HWc + p);

        // ---- issue the 24 loads of this iteration, then fence ----
        float4 pv[4], gv[4];
        int4 pmv[Nc], gmv[Nc];
#pragma unroll
        for (int c = 0; c < 4; ++c) pv[c] = pd4[c * HW4];
#pragma unroll
        for (int c = 0; c < 4; ++c) gv[c] = gt4[c * HW4];
#pragma unroll
        for (int n = 0; n < Nc; ++n) { pmv[n] = pm4[n * HW4]; gmv[n] = gm4[n * HW4]; }
        __builtin_amdgcn_sched_barrier(0);   // loads stay batched ahead of uses

        // ---- per-pixel quantities ----
        float dn[4], po[4], go[4];
        {
            float dx, dy, dz;
            dx = pv[0].x - gv[0].x; dy = pv[1].x - gv[1].x; dz = pv[2].x - gv[2].x;
            dn[0] = sqrtf(dx*dx + dy*dy + dz*dz); po[0] = rintf(pv[3].x); go[0] = rintf(gv[3].x);
            dx = pv[0].y - gv[0].y; dy = pv[1].y - gv[1].y; dz = pv[2].y - gv[2].y;
            dn[1] = sqrtf(dx*dx + dy*dy + dz*dz); po[1] = rintf(pv[3].y); go[1] = rintf(gv[3].y);
            dx = pv[0].z - gv[0].z; dy = pv[1].z - gv[1].z; dz = pv[2].z - gv[2].z;
            dn[2] = sqrtf(dx*dx + dy*dy + dz*dz); po[2] = rintf(pv[3].z); go[2] = rintf(gv[3].z);
            dx = pv[0].w - gv[0].w; dy = pv[1].w - gv[1].w; dz = pv[2].w - gv[2].w;
            dn[3] = sqrtf(dx*dx + dy*dy + dz*dz); po[3] = rintf(pv[3].w); go[3] = rintf(gv[3].w);
        }

#pragma unroll
        for (int n = 0; n < Nc; ++n) {
            const int pmx[4] = {pmv[n].x, pmv[n].y, pmv[n].z, pmv[n].w};
            const int gmx[4] = {gmv[n].x, gmv[n].y, gmv[n].z, gmv[n].w};
#pragma unroll
            for (int j = 0; j < 4; ++j) {
                const bool P = pmx[j] != 0;
                const bool G = gmx[j] != 0;
                wcnt[n] += __popcll(__ballot(P));
                const float s = P ? po[j] : 0.f;
                acc[n][0] += P ? dn[j] : 0.f;
                acc[n][1] += G ? s     : 0.f;   // inter = (P&&G)?po:0
                acc[n][2] += G ? go[j] : 0.f;
                acc[n][3] += s;                 // xor = s_sum - inter (in final)
            }
        }
    }

    // ---- LDS-transpose block reduction (2 waves) ----
    __shared__ float tr[TPB][33];    // stride 33: conflict-free both phases
    __shared__ float part[2][32];
    __shared__ float cpart[2][Nc];

    const int lane = tid & 63;
    const int wv   = tid >> 6;
#pragma unroll
    for (int qi = 0; qi < 32; ++qi) tr[tid][qi] = acc[qi >> 2][qi & 3];
    if (lane == 0) {
#pragma unroll
        for (int n = 0; n < Nc; ++n) cpart[wv][n] = (float)wcnt[n];
    }
    __syncthreads();

    {
        const int q    = tid & 31;   // quantity (n*4 + {sim,inter,gt,s})
        const int half = tid >> 5;   // quarter of rows: 32 each
        float s = 0.f;
#pragma unroll
        for (int k = 0; k < 32; ++k) s += tr[half * 32 + k][q];
        s += __shfl_xor(s, 32, 64);          // rows 0-63 in wave0, 64-127 in wave1
        if ((tid & 32) == 0) part[wv][q] = s;
    }
    __syncthreads();

    if (tid < 32) {
        const float v = part[0][tid] + part[1][tid];
        const int n = tid >> 2, qq = tid & 3;
        const int slot = n * 5 + (qq == 0 ? 0 : qq + 1);  // sim->0 inter->2 gt->3 s->4
        atomicAdd(&ws[(b * 40 + slot) * PAD], v);
    } else if (tid >= 64 && tid < 64 + Nc) {
        const int n = tid - 64;
        atomicAdd(&ws[(b * 40 + n * 5 + 1) * PAD], cpart[0][n] + cpart[1][n]);
    }
}

__global__ __launch_bounds__(64) void niou_final(
    const float* __restrict__ ws, float* __restrict__ out)
{
    const int t = threadIdx.x;   // 0..63 == b*8+n
    const float* w = ws + (size_t)t * 5 * PAD;
    const float sim   = w[0 * PAD];
    const float cnt   = w[1 * PAD];
    const float inter = w[2 * PAD];
    const float gts   = w[3 * PAD];
    const float ssum  = w[4 * PAD];
    const float xo    = ssum - inter;            // pd_xor_sum
    const float punish = sim / (cnt + EPSc);
    const float iou    = inter / (gts + xo + EPSc);
    float term = 1.0f - iou + punish;
#pragma unroll
    for (int off = 32; off; off >>= 1) term += __shfl_xor(term, off, 64);
    if (t == 0) out[0] = term * (1.0f / 64.0f);
}

extern "C" void kernel_launch(void* const* d_in, const int* in_sizes, int n_in,
                              void* d_out, int out_size, void* d_ws, size_t ws_size,
                              hipStream_t stream) {
    const float* pd_rgbo = (const float*)d_in[0];
    const float* gt_rgbo = (const float*)d_in[1];
    const int*   pd_mask = (const int*)d_in[2];
    const int*   gt_mask = (const int*)d_in[3];
    float* out = (float*)d_out;
    float* ws  = (float*)d_ws;

    hipMemsetAsync(ws, 0, Bc * 40 * PAD * sizeof(float), stream);
    niou_partial<<<Bc * 256, TPB, 0, stream>>>(pd_rgbo, gt_rgbo, pd_mask, gt_mask, ws);
    niou_final<<<1, 64, 0, stream>>>(ws, out);
}

// Round 10
// 40.981 us; speedup vs baseline: 2.2190x; 1.3438x over previous
//
#include <hip/hip_runtime.h>

// NIoULoss_pixel: B=8, N=8, H=W=512. One-pass fused reduction.
// R10: R8's two-phase thin-thread structure (12 loads/thread, occ 66%) with
// the real R8 killer removed: 327K same-line atomics (1024 RMW/line) are
// replaced by NON-atomic per-block partials part[320][1024] in d_ws + a
// 320-block reduce kernel. R9 post-mortem: fat-batch ILP spilled (WRITE 33MB)
// — that program is dead; this is the TLP program, properly measured.

constexpr int Bc  = 8;
constexpr int Nc  = 8;
constexpr int HWc = 512 * 512;
constexpr int BPI = 1024;             // blocks per image (256 px per block)
constexpr float EPSc = 1e-6f;

__device__ __forceinline__ float wave_reduce(float v) {
#pragma unroll
    for (int off = 32; off; off >>= 1) v += __shfl_xor(v, off, 64);
    return v;
}

// 8192 blocks, 256 threads, 256 pixels/block.
// Phase 1: thread -> one pixel's dn/po/go (8 scalar coalesced loads) -> LDS.
// Phase 2: thread (g=tid>>6, q=tid&63) -> planes 2g,2g+1 of quad q (4 int4).
// Wave g owns its plane pair: epilogue is wave-reduce + lane0 plain stores.
template<bool USE_PART>
__global__ __launch_bounds__(256) void niou_partial(
    const float* __restrict__ pd, const float* __restrict__ gt,
    const int* __restrict__ pmask, const int* __restrict__ gmask,
    float* __restrict__ outp /* USE_PART ? part[320][BPI] : ws atomic [320][16] */)
{
    __shared__ float dnL[264], poL[264], goL[264];   // si(p)=p+(p>>5)

    const int tid  = threadIdx.x;
    const int b    = blockIdx.x >> 10;
    const int blk  = blockIdx.x & 1023;
    const int base = blk * 256;
    const int pix  = base + tid;

    // ---- issue rgbo loads (oldest in queue): 8 scalar, fully coalesced ----
    const float* pdB = pd + (size_t)b * 4 * HWc + pix;
    const float* gtB = gt + (size_t)b * 4 * HWc + pix;
    float pr[4], gr[4];
#pragma unroll
    for (int c = 0; c < 4; ++c) pr[c] = pdB[(size_t)c * HWc];
#pragma unroll
    for (int c = 0; c < 4; ++c) gr[c] = gtB[(size_t)c * HWc];

    // ---- issue mask loads: thread (g,q) -> planes 2g,2g+1 at quad q ----
    const int g = tid >> 6, q = tid & 63;
    const int qb = base + 4 * q;
    int4 pmv[2], gmv[2];
    pmv[0] = *reinterpret_cast<const int4*>(pmask + (size_t)(b * Nc + 2 * g    ) * HWc + qb);
    gmv[0] = *reinterpret_cast<const int4*>(gmask + (size_t)(b * Nc + 2 * g    ) * HWc + qb);
    pmv[1] = *reinterpret_cast<const int4*>(pmask + (size_t)(b * Nc + 2 * g + 1) * HWc + qb);
    gmv[1] = *reinterpret_cast<const int4*>(gmask + (size_t)(b * Nc + 2 * g + 1) * HWc + qb);
    __builtin_amdgcn_sched_barrier(0);   // keep all 12 loads issued up front

    // ---- phase 1: this thread's pixel -> LDS (waits only on rgbo) ----
    {
        const float dx = pr[0] - gr[0], dy = pr[1] - gr[1], dz = pr[2] - gr[2];
        const int si = tid + (tid >> 5);
        dnL[si] = sqrtf(dx * dx + dy * dy + dz * dz);
        poL[si] = rintf(pr[3]);
        goL[si] = rintf(gr[3]);
    }
    __syncthreads();

    // ---- phase 2: masks (long since landed) + LDS pixel quantities ----
    float dn[4], po[4], go[4];
#pragma unroll
    for (int j = 0; j < 4; ++j) {
        const int p4 = 4 * q + j, s4 = p4 + (p4 >> 5);
        dn[j] = dnL[s4]; po[j] = poL[s4]; go[j] = goL[s4];
    }

    // acc[pp]: {sim_sum, inter, gt_sum, s_sum}; count via ballot (wave-uniform)
    float acc[2][4];
    int   wcnt[2];
#pragma unroll
    for (int pp = 0; pp < 2; ++pp) {
        wcnt[pp] = 0;
#pragma unroll
        for (int k = 0; k < 4; ++k) acc[pp][k] = 0.f;
    }

#pragma unroll
    for (int pp = 0; pp < 2; ++pp) {
        const int pmx[4] = {pmv[pp].x, pmv[pp].y, pmv[pp].z, pmv[pp].w};
        const int gmx[4] = {gmv[pp].x, gmv[pp].y, gmv[pp].z, gmv[pp].w};
#pragma unroll
        for (int j = 0; j < 4; ++j) {
            const bool P = pmx[j] != 0;
            const bool G = gmx[j] != 0;
            wcnt[pp] += __popcll(__ballot(P));
            const float s = P ? po[j] : 0.f;
            acc[pp][0] += P ? dn[j] : 0.f;
            acc[pp][1] += G ? s     : 0.f;   // inter = (P&&G)?po:0
            acc[pp][2] += G ? go[j] : 0.f;
            acc[pp][3] += s;                 // xor = s_sum - inter (in final)
        }
    }

    // ---- wave-level reduction; lane0 stores 10 partials (NO atomics) ----
    const int lane = tid & 63;
#pragma unroll
    for (int pp = 0; pp < 2; ++pp) {
        const float s0 = wave_reduce(acc[pp][0]);
        const float s1 = wave_reduce(acc[pp][1]);
        const float s2 = wave_reduce(acc[pp][2]);
        const float s3 = wave_reduce(acc[pp][3]);
        if (lane == 0) {
            const int n = 2 * g + pp;
            if (USE_PART) {
                float* dst = outp + (size_t)(b * 40 + n * 5) * BPI + blk;
                dst[0 * BPI] = s0;
                dst[1 * BPI] = (float)wcnt[pp];
                dst[2 * BPI] = s1;
                dst[3 * BPI] = s2;
                dst[4 * BPI] = s3;
            } else {   // fallback: proven 20KB atomic layout (PAD=16)
                float* wsn = outp + (size_t)(b * 40 + n * 5) * 16;
                atomicAdd(&wsn[0 * 16], s0);
                atomicAdd(&wsn[1 * 16], (float)wcnt[pp]);
                atomicAdd(&wsn[2 * 16], s1);
                atomicAdd(&wsn[3 * 16], s2);
                atomicAdd(&wsn[4 * 16], s3);
            }
        }
    }
}

// 320 blocks x 256 threads: sums[slot] = sum over BPI per-block partials.
__global__ __launch_bounds__(256) void niou_reduce(
    const float* __restrict__ part, float* __restrict__ sums)
{
    const int slot = blockIdx.x;     // 0..319
    const int tid  = threadIdx.x;
    float s = 0.f;
#pragma unroll
    for (int i = 0; i < BPI; i += 256) s += part[(size_t)slot * BPI + i + tid];
    s = wave_reduce(s);
    __shared__ float w4[4];
    if ((tid & 63) == 0) w4[tid >> 6] = s;
    __syncthreads();
    if (tid == 0) sums[slot] = w4[0] + w4[1] + w4[2] + w4[3];
}

__global__ __launch_bounds__(64) void niou_final(
    const float* __restrict__ w0, float* __restrict__ out, int pad)
{
    const int t = threadIdx.x;   // 0..63 == b*8+n
    const float* w = w0 + (size_t)t * 5 * pad;
    const float sim   = w[0 * pad];
    const float cnt   = w[1 * pad];
    const float inter = w[2 * pad];
    const float gts   = w[3 * pad];
    const float ssum  = w[4 * pad];
    const float xo    = ssum - inter;            // pd_xor_sum
    const float punish = sim / (cnt + EPSc);
    const float iou    = inter / (gts + xo + EPSc);
    float term = 1.0f - iou + punish;
#pragma unroll
    for (int off = 32; off; off >>= 1) term += __shfl_xor(term, off, 64);
    if (t == 0) out[0] = term * (1.0f / 64.0f);
}

extern "C" void kernel_launch(void* const* d_in, const int* in_sizes, int n_in,
                              void* d_out, int out_size, void* d_ws, size_t ws_size,
                              hipStream_t stream) {
    const float* pd_rgbo = (const float*)d_in[0];
    const float* gt_rgbo = (const float*)d_in[1];
    const int*   pd_mask = (const int*)d_in[2];
    const int*   gt_mask = (const int*)d_in[3];
    float* out = (float*)d_out;
    float* ws  = (float*)d_ws;

    const size_t need = ((size_t)320 * BPI + 320) * sizeof(float);
    if (ws_size >= need) {
        float* part = ws;
        float* sums = ws + (size_t)320 * BPI;
        niou_partial<true><<<Bc * BPI, 256, 0, stream>>>(pd_rgbo, gt_rgbo,
                                                         pd_mask, gt_mask, part);
        niou_reduce<<<320, 256, 0, stream>>>(part, sums);
        niou_final<<<1, 64, 0, stream>>>(sums, out, 1);
    } else {
        hipMemsetAsync(ws, 0, 320 * 16 * sizeof(float), stream);
        niou_partial<false><<<Bc * BPI, 256, 0, stream>>>(pd_rgbo, gt_rgbo,
                                                          pd_mask, gt_mask, ws);
        niou_final<<<1, 64, 0, stream>>>(ws, out, 16);
    }
}

// Round 11
// 38.607 us; speedup vs baseline: 2.3554x; 1.0615x over previous
//
#include <hip/hip_runtime.h>

// NIoULoss_pixel: B=8, N=8, H=W=512. One-pass fused reduction.
// R11: the untested cell of the (per-wave MLP x occupancy) matrix.
// R10's thin two-phase structure + partials epilogue (occ 76%, 41us) but all
// 16 loads asm-volatile pinned in fixed order (R7's discipline) with counted
// vmcnt drains. 512 px/block: phase1 = 2 px/thread via dwordx2 rgbo loads;
// phase2 = planes 2g,2g+1 x quads {q,q+64} = 8 int4 mask loads in flight
// through the phase1+barrier window. LDS unpadded: b64 writes / b128 reads,
// both conflict-free. launch_bounds(256,4): 128-VGPR cap, no spill (R9 lesson).

constexpr int Bc  = 8;
constexpr int Nc  = 8;
constexpr int HWc = 512 * 512;
constexpr int BPI = 512;              // blocks per image (512 px per block)
constexpr float EPSc = 1e-6f;

__device__ __forceinline__ float2 gload_f2(const float* a) {
    float2 r;
    asm volatile("global_load_dwordx2 %0, %1, off" : "=v"(r) : "v"(a) : "memory");
    return r;
}
__device__ __forceinline__ int4 gload_i4(const int* a) {
    int4 r;
    asm volatile("global_load_dwordx4 %0, %1, off" : "=v"(r) : "v"(a) : "memory");
    return r;
}
#define WAITV(n_) do {                                                   \
        asm volatile("s_waitcnt vmcnt(" #n_ ")" ::: "memory");           \
        __builtin_amdgcn_sched_barrier(0);                               \
    } while (0)

__device__ __forceinline__ float wave_reduce(float v) {
#pragma unroll
    for (int off = 32; off; off >>= 1) v += __shfl_xor(v, off, 64);
    return v;
}

// 4096 blocks, 256 threads, 512 pixels/block.
template<bool USE_PART>
__global__ __launch_bounds__(256, 4) void niou_partial(
    const float* __restrict__ pd, const float* __restrict__ gt,
    const int* __restrict__ pmask, const int* __restrict__ gmask,
    float* __restrict__ outp /* USE_PART ? part[320][BPI] : ws atomic [320][16] */)
{
    __shared__ float dnL[512], poL[512], goL[512];   // unpadded: b64 W / b128 R

    const int tid  = threadIdx.x;
    const int b    = blockIdx.x >> 9;
    const int blk  = blockIdx.x & 511;
    const int base = blk * 512;

    // ---- issue 8 rgbo dwordx2 loads (oldest in queue) ----
    const float* pdB = pd + (size_t)b * 4 * HWc + base + 2 * tid;
    const float* gtB = gt + (size_t)b * 4 * HWc + base + 2 * tid;
    float2 pr[4], gr[4];
#pragma unroll
    for (int c = 0; c < 4; ++c) pr[c] = gload_f2(pdB + (size_t)c * HWc);
#pragma unroll
    for (int c = 0; c < 4; ++c) gr[c] = gload_f2(gtB + (size_t)c * HWc);

    // ---- issue 8 mask int4 loads: planes 2g,2g+1, quads q and q+64 ----
    const int g = tid >> 6, q = tid & 63;
    int4 pmv[2][2], gmv[2][2];   // [plane pp][quad qq]
#pragma unroll
    for (int pp = 0; pp < 2; ++pp) {
        const size_t pl = (size_t)(b * Nc + 2 * g + pp) * HWc + base + 4 * q;
#pragma unroll
        for (int qq = 0; qq < 2; ++qq) {
            pmv[pp][qq] = gload_i4(pmask + pl + 256 * qq);
            gmv[pp][qq] = gload_i4(gmask + pl + 256 * qq);
        }
    }

    // ---- rgbo done (8 oldest); 8 mask loads still in flight ----
    WAITV(8);
    {
        const float dx0 = pr[0].x - gr[0].x, dy0 = pr[1].x - gr[1].x, dz0 = pr[2].x - gr[2].x;
        const float dx1 = pr[0].y - gr[0].y, dy1 = pr[1].y - gr[1].y, dz1 = pr[2].y - gr[2].y;
        float2 d2, p2, g2;
        d2.x = sqrtf(dx0*dx0 + dy0*dy0 + dz0*dz0);
        d2.y = sqrtf(dx1*dx1 + dy1*dy1 + dz1*dz1);
        p2.x = rintf(pr[3].x); p2.y = rintf(pr[3].y);
        g2.x = rintf(gr[3].x); g2.y = rintf(gr[3].y);
        *reinterpret_cast<float2*>(&dnL[2 * tid]) = d2;
        *reinterpret_cast<float2*>(&poL[2 * tid]) = p2;
        *reinterpret_cast<float2*>(&goL[2 * tid]) = g2;
    }
    __syncthreads();

    // ---- masks guaranteed landed; consume ----
    WAITV(0);
    float4 dnq[2], poq[2], goq[2];
#pragma unroll
    for (int qq = 0; qq < 2; ++qq) {
        const int li = 256 * qq + 4 * q;
        dnq[qq] = *reinterpret_cast<const float4*>(&dnL[li]);
        poq[qq] = *reinterpret_cast<const float4*>(&poL[li]);
        goq[qq] = *reinterpret_cast<const float4*>(&goL[li]);
    }

    // acc[pp]: {sim_sum, inter, gt_sum, s_sum}; count via ballot
    float acc[2][4];
    int   wcnt[2];
#pragma unroll
    for (int pp = 0; pp < 2; ++pp) {
        wcnt[pp] = 0;
#pragma unroll
        for (int k = 0; k < 4; ++k) acc[pp][k] = 0.f;
    }

#pragma unroll
    for (int pp = 0; pp < 2; ++pp)
#pragma unroll
        for (int qq = 0; qq < 2; ++qq) {
            const int pmx[4] = {pmv[pp][qq].x, pmv[pp][qq].y, pmv[pp][qq].z, pmv[pp][qq].w};
            const int gmx[4] = {gmv[pp][qq].x, gmv[pp][qq].y, gmv[pp][qq].z, gmv[pp][qq].w};
            const float dnj[4] = {dnq[qq].x, dnq[qq].y, dnq[qq].z, dnq[qq].w};
            const float poj[4] = {poq[qq].x, poq[qq].y, poq[qq].z, poq[qq].w};
            const float goj[4] = {goq[qq].x, goq[qq].y, goq[qq].z, goq[qq].w};
#pragma unroll
            for (int j = 0; j < 4; ++j) {
                const bool P = pmx[j] != 0;
                const bool G = gmx[j] != 0;
                wcnt[pp] += __popcll(__ballot(P));
                const float s = P ? poj[j] : 0.f;
                acc[pp][0] += P ? dnj[j] : 0.f;
                acc[pp][1] += G ? s      : 0.f;   // inter = (P&&G)?po:0
                acc[pp][2] += G ? goj[j] : 0.f;
                acc[pp][3] += s;                  // xor = s_sum - inter (final)
            }
        }

    // ---- wave-level reduction; lane0 stores 10 partials (no atomics) ----
    const int lane = tid & 63;
#pragma unroll
    for (int pp = 0; pp < 2; ++pp) {
        const float s0 = wave_reduce(acc[pp][0]);
        const float s1 = wave_reduce(acc[pp][1]);
        const float s2 = wave_reduce(acc[pp][2]);
        const float s3 = wave_reduce(acc[pp][3]);
        if (lane == 0) {
            const int n = 2 * g + pp;
            if (USE_PART) {
                float* dst = outp + (size_t)(b * 40 + n * 5) * BPI + blk;
                dst[0 * BPI] = s0;
                dst[1 * BPI] = (float)wcnt[pp];
                dst[2 * BPI] = s1;
                dst[3 * BPI] = s2;
                dst[4 * BPI] = s3;
            } else {   // fallback: proven 20KB atomic layout (PAD=16)
                float* wsn = outp + (size_t)(b * 40 + n * 5) * 16;
                atomicAdd(&wsn[0 * 16], s0);
                atomicAdd(&wsn[1 * 16], (float)wcnt[pp]);
                atomicAdd(&wsn[2 * 16], s1);
                atomicAdd(&wsn[3 * 16], s2);
                atomicAdd(&wsn[4 * 16], s3);
            }
        }
    }
}

// 320 blocks x 256 threads: sums[slot] = sum of BPI per-block partials.
__global__ __launch_bounds__(256) void niou_reduce(
    const float* __restrict__ part, float* __restrict__ sums)
{
    const int slot = blockIdx.x;     // 0..319
    const int tid  = threadIdx.x;
    float s = 0.f;
#pragma unroll
    for (int i = 0; i < BPI; i += 256) s += part[(size_t)slot * BPI + i + tid];
    s = wave_reduce(s);
    __shared__ float w4[4];
    if ((tid & 63) == 0) w4[tid >> 6] = s;
    __syncthreads();
    if (tid == 0) sums[slot] = w4[0] + w4[1] + w4[2] + w4[3];
}

__global__ __launch_bounds__(64) void niou_final(
    const float* __restrict__ w0, float* __restrict__ out, int pad)
{
    const int t = threadIdx.x;   // 0..63 == b*8+n
    const float* w = w0 + (size_t)t * 5 * pad;
    const float sim   = w[0 * pad];
    const float cnt   = w[1 * pad];
    const float inter = w[2 * pad];
    const float gts   = w[3 * pad];
    const float ssum  = w[4 * pad];
    const float xo    = ssum - inter;            // pd_xor_sum
    const float punish = sim / (cnt + EPSc);
    const float iou    = inter / (gts + xo + EPSc);
    float term = 1.0f - iou + punish;
#pragma unroll
    for (int off = 32; off; off >>= 1) term += __shfl_xor(term, off, 64);
    if (t == 0) out[0] = term * (1.0f / 64.0f);
}

extern "C" void kernel_launch(void* const* d_in, const int* in_sizes, int n_in,
                              void* d_out, int out_size, void* d_ws, size_t ws_size,
                              hipStream_t stream) {
    const float* pd_rgbo = (const float*)d_in[0];
    const float* gt_rgbo = (const float*)d_in[1];
    const int*   pd_mask = (const int*)d_in[2];
    const int*   gt_mask = (const int*)d_in[3];
    float* out = (float*)d_out;
    float* ws  = (float*)d_ws;

    const size_t need = ((size_t)320 * BPI + 320) * sizeof(float);
    if (ws_size >= need) {
        float* part = ws;
        float* sums = ws + (size_t)320 * BPI;
        niou_partial<true><<<Bc * BPI, 256, 0, stream>>>(pd_rgbo, gt_rgbo,
                                                         pd_mask, gt_mask, part);
        niou_reduce<<<320, 256, 0, stream>>>(part, sums);
        niou_final<<<1, 64, 0, stream>>>(sums, out, 1);
    } else {
        hipMemsetAsync(ws, 0, 320 * 16 * sizeof(float), stream);
        niou_partial<false><<<Bc * BPI, 256, 0, stream>>>(pd_rgbo, gt_rgbo,
                                                          pd_mask, gt_mask, ws);
        niou_final<<<1, 64, 0, stream>>>(ws, out, 16);
    }
}